// Round 4
// baseline (2210.943 us; speedup 1.0000x reference)
//
#include <hip/hip_runtime.h>
#include <math.h>

// Problem constants
#define BB 16
#define NN 8192
#define SS 1024
#define GG 32
#define MTOT (BB*SS*GG)   // 524288
// MLP: 6 -> 64 -> 64 -> 128

struct alignas(16) f4 { float v[4]; };

// ---------------------------------------------------------------------------
// prep: transpose raw weights: w2T[k][o] (64x64), w3T[k][o] (64x128)
// ---------------------------------------------------------------------------
__global__ __launch_bounds__(512) void prep_kernel(const float* __restrict__ w1g,
                                                   const float* __restrict__ w2g,
                                                   float* __restrict__ w2T,
                                                   float* __restrict__ w3T)
{
    const int tid = threadIdx.x;
    for (int i = tid; i < 4096; i += 512) w2T[(i & 63) * 64 + (i >> 6)] = w1g[i];
    for (int i = tid; i < 8192; i += 512) w3T[(i & 63) * 128 + (i >> 6)] = w2g[i];
}

// ---------------------------------------------------------------------------
// Kernel: farthest point sampling. One block per batch, 256 threads, 32 pts
// per thread in registers; coords in LDS for centroid lookup.
// Cross-wave sync per step is a release/acquire FLAG protocol in LDS (no
// __syncthreads in the loop): each wave publishes its packed u64 winner key
// (parity double-buffered) then bumps a monotone flag; others spin-acquire.
// WAR safety: skey[s&1] is only overwritten at step s+2, which is gated on
// all flags >= s+2, implying every wave finished its step-s reads.
// Exact f32 semantics (no FMA contraction); argmax ties -> lowest index.
// ---------------------------------------------------------------------------
__global__ __launch_bounds__(256) void fps_kernel(const float* __restrict__ xyz,
                                                  float* __restrict__ newxyz)
{
    __shared__ float lx[NN], ly[NN], lz[NN];            // 96 KB
    __shared__ unsigned long long skey[2][4];
    __shared__ int sflag[4];
    const int b = blockIdx.x;
    const int t = threadIdx.x;
    const int wave = t >> 6, lane = t & 63;
    const float* base = xyz + (size_t)b * NN * 3;

    if (t < 4) sflag[t] = 0;

    float px[32], py[32], pz[32], dd[32];
#pragma unroll
    for (int k = 0; k < 32; ++k) {
        const int p = (k << 8) + t;
        const float x = base[p * 3 + 0];
        const float y = base[p * 3 + 1];
        const float z = base[p * 3 + 2];
        px[k] = x; py[k] = y; pz[k] = z; dd[k] = 1e10f;
        lx[p] = x; ly[p] = y; lz[p] = z;
    }
    __syncthreads();   // only barrier: staging + flag init

    int far = 0;
    float* outb = newxyz + (size_t)b * SS * 3;
    for (int s = 0; s < SS; ++s) {
        const float cx = lx[far], cy = ly[far], cz = lz[far];
        if (t == 0) {
            outb[s * 3 + 0] = cx;
            outb[s * 3 + 1] = cy;
            outb[s * 3 + 2] = cz;
        }
        float bf = -1.f;
        int   bi = 0;
#pragma unroll
        for (int k = 0; k < 32; ++k) {
            const float dx = __fsub_rn(px[k], cx);
            const float dy = __fsub_rn(py[k], cy);
            const float dz = __fsub_rn(pz[k], cz);
            const float d  = __fadd_rn(__fadd_rn(__fmul_rn(dx, dx), __fmul_rn(dy, dy)),
                                       __fmul_rn(dz, dz));
            const float nd = fminf(dd[k], d);
            dd[k] = nd;
            const bool c = nd > bf;              // strict > keeps lowest k
            bf = c ? nd : bf;
            bi = c ? ((k << 8) + t) : bi;
        }
        unsigned long long best =
            ((unsigned long long)__float_as_uint(bf) << 32) |
            (unsigned long long)(0xFFFFFFFFu - (unsigned)bi);
#pragma unroll
        for (int off = 32; off > 0; off >>= 1) {
            const unsigned long long o = __shfl_xor(best, off);
            best = (o > best) ? o : best;
        }
        if (lane == 0) {
            skey[s & 1][wave] = best;
            __hip_atomic_store(&sflag[wave], s + 1, __ATOMIC_RELEASE,
                               __HIP_MEMORY_SCOPE_WORKGROUP);
        }
#pragma unroll
        for (int w = 0; w < 4; ++w) {
            if (w == wave) continue;
            while (__hip_atomic_load(&sflag[w], __ATOMIC_ACQUIRE,
                                     __HIP_MEMORY_SCOPE_WORKGROUP) <= s) {}
        }
        unsigned long long g = skey[s & 1][0];
#pragma unroll
        for (int w = 1; w < 4; ++w) {
            const unsigned long long o = skey[s & 1][w];
            g = (o > g) ? o : g;
        }
        far = (int)(0xFFFFFFFFu - (unsigned)(g & 0xFFFFFFFFull));
    }
}

// ---------------------------------------------------------------------------
// ball query + gather + v first/second moments (for analytic BN1 stats).
// One wave per centroid; first 32 hits in index order; pad with first hit.
// ---------------------------------------------------------------------------
__global__ __launch_bounds__(256) void ball_gather_kernel(const float* __restrict__ xyz,
                                                          const float* __restrict__ feat,
                                                          const float* __restrict__ newxyz,
                                                          float* __restrict__ v,
                                                          float* __restrict__ part1)
{
    const int wid  = (int)((blockIdx.x * 256 + threadIdx.x) >> 6);
    const int lane = threadIdx.x & 63;
    if (wid >= BB * SS) return;
    const int b = wid >> 10;

    const float cx = newxyz[wid * 3 + 0];
    const float cy = newxyz[wid * 3 + 1];
    const float cz = newxyz[wid * 3 + 2];
    const float* xb = xyz + (size_t)b * NN * 3;
    const float* fb = feat + (size_t)b * NN * 3;
    const size_t mbase = (size_t)wid * GG;

    float mS[6];
    float mP[36];
#pragma unroll
    for (int c = 0; c < 6; ++c) mS[c] = 0.f;
#pragma unroll
    for (int c = 0; c < 36; ++c) mP[c] = 0.f;

    int cnt = 0, firstp = -1;
    for (int base = 0; base < NN && cnt < GG; base += 64) {
        const int p = base + lane;
        const float x = xb[p * 3 + 0], y = xb[p * 3 + 1], z = xb[p * 3 + 2];
        const float dx = __fsub_rn(cx, x);
        const float dy = __fsub_rn(cy, y);
        const float dz = __fsub_rn(cz, z);
        const float d  = __fadd_rn(__fadd_rn(__fmul_rn(dx, dx), __fmul_rn(dy, dy)),
                                   __fmul_rn(dz, dz));
        const bool hit = (d <= 0.04f);
        const unsigned long long m = __ballot(hit);
        if (firstp < 0 && m != 0ull) firstp = base + (int)__builtin_ctzll(m);
        const int pos = cnt + (int)__popcll(m & ((1ull << lane) - 1ull));
        if (hit && pos < GG) {
            const size_t mm = mbase + pos;
            float a[6];
            a[0] = __fsub_rn(x, cx);
            a[1] = __fsub_rn(y, cy);
            a[2] = __fsub_rn(z, cz);
            a[3] = fb[p * 3 + 0];
            a[4] = fb[p * 3 + 1];
            a[5] = fb[p * 3 + 2];
#pragma unroll
            for (int c = 0; c < 6; ++c) {
                v[(size_t)c * MTOT + mm] = a[c];
                mS[c] += a[c];
#pragma unroll
                for (int dch = 0; dch < 6; ++dch)
                    mP[c * 6 + dch] = fmaf(a[c], a[dch], mP[c * 6 + dch]);
            }
        }
        cnt += (int)__popcll(m);
    }
    if (cnt < GG) {
        const int p = firstp;
        const float x = xb[p * 3 + 0], y = xb[p * 3 + 1], z = xb[p * 3 + 2];
        float a[6];
        a[0] = __fsub_rn(x, cx);
        a[1] = __fsub_rn(y, cy);
        a[2] = __fsub_rn(z, cz);
        a[3] = fb[p * 3 + 0];
        a[4] = fb[p * 3 + 1];
        a[5] = fb[p * 3 + 2];
        for (int j = cnt + lane; j < GG; j += 64) {
            const size_t mm = mbase + j;
#pragma unroll
            for (int c = 0; c < 6; ++c) {
                v[(size_t)c * MTOT + mm] = a[c];
                mS[c] += a[c];
#pragma unroll
                for (int dch = 0; dch < 6; ++dch)
                    mP[c * 6 + dch] = fmaf(a[c], a[dch], mP[c * 6 + dch]);
            }
        }
    }
#pragma unroll
    for (int off = 1; off < 64; off <<= 1) {
#pragma unroll
        for (int c = 0; c < 6; ++c) mS[c] += __shfl_xor(mS[c], off);
#pragma unroll
        for (int c = 0; c < 36; ++c) mP[c] += __shfl_xor(mP[c], off);
    }
    if (lane == 0) {
        float* row = part1 + (size_t)wid * 42;
#pragma unroll
        for (int c = 0; c < 6; ++c) row[c] = mS[c];
#pragma unroll
        for (int c = 0; c < 36; ++c) row[6 + c] = mP[c];
    }
}

// ---------------------------------------------------------------------------
// finalize1: reduce v moments (16384 x 42), analytic BN1 stats of x1 = W1 v
// (bias cancels in BN); write folded w1S[c][o] = A1[o]*w1[o][c] and
// c1[o] = beta1[o] - A1[o]*mean_nb[o].
// ---------------------------------------------------------------------------
__global__ __launch_bounds__(512) void finalize1_kernel(const float* __restrict__ part1,
                                                        const float* __restrict__ w0,
                                                        const float* __restrict__ g0,
                                                        const float* __restrict__ bt0,
                                                        float* __restrict__ w1S,
                                                        float* __restrict__ c1)
{
    __shared__ double red[504];
    __shared__ double tot[42];
    const int tid = threadIdx.x;
    if (tid < 504) {
        const int j = tid % 42, r = tid / 42;   // 12 reducers per channel
        double s = 0.0;
        for (int i = r; i < BB * SS; i += 12) s += (double)part1[(size_t)i * 42 + j];
        red[tid] = s;
    }
    __syncthreads();
    if (tid < 42) {
        double s = 0.0;
        for (int r = 0; r < 12; ++r) s += red[r * 42 + tid];
        tot[tid] = s / (double)MTOT;
    }
    __syncthreads();
    if (tid < 64) {
        double m1 = 0.0;
        for (int c = 0; c < 6; ++c) m1 += (double)w0[tid * 6 + c] * tot[c];
        double e2 = 0.0;
        for (int c = 0; c < 6; ++c)
            for (int d = 0; d < 6; ++d)
                e2 += (double)w0[tid * 6 + c] * (double)w0[tid * 6 + d] * tot[6 + c * 6 + d];
        double var = e2 - m1 * m1;
        if (var < 0.0) var = 0.0;
        const double A = (double)g0[tid] / sqrt(var + 1e-5);
        c1[tid] = (float)((double)bt0[tid] - A * m1);
        for (int c = 0; c < 6; ++c)
            w1S[c * 64 + tid] = (float)(A * (double)w0[tid * 6 + c]);
    }
}

// ---------------------------------------------------------------------------
// finalize2: reduce stats2 partials (512 blocks x [s256|q256]) -> A2/c2,
// write folded w2S = A2 o* w2T.
// ---------------------------------------------------------------------------
__global__ __launch_bounds__(512) void finalize2_kernel(const float* __restrict__ part,
                                                        const float* __restrict__ w2T,
                                                        const float* __restrict__ g1,
                                                        const float* __restrict__ bt1,
                                                        float* __restrict__ w2S,
                                                        float* __restrict__ c2)
{
    __shared__ double tot[512];
    __shared__ float As[64];
    const int tid = threadIdx.x;
    double s = 0.0;
    for (int blk = 0; blk < 512; ++blk) s += (double)part[(size_t)blk * 512 + tid];
    tot[tid] = s;
    __syncthreads();
    if (tid < 64) {
        double S = 0.0, Q = 0.0;
        for (int g = 0; g < 4; ++g) { S += tot[g * 64 + tid]; Q += tot[256 + g * 64 + tid]; }
        const double mean = S / (double)MTOT;
        double var = Q / (double)MTOT - mean * mean;
        if (var < 0.0) var = 0.0;
        const double A = (double)g1[tid] / sqrt(var + 1e-5);
        As[tid] = (float)A;
        c2[tid] = (float)((double)bt1[tid] - A * mean);
    }
    __syncthreads();
    for (int i = tid; i < 4096; i += 512) w2S[i] = As[i & 63] * w2T[i];
}

// ---------------------------------------------------------------------------
// finalize3: reduce stats3 partials (512 blocks x [s256|q256|s256|q256]) ->
// A3/c3, write folded w3S = A3 o* w3T.
// ---------------------------------------------------------------------------
__global__ __launch_bounds__(512) void finalize3_kernel(const float* __restrict__ part,
                                                        const float* __restrict__ w3T,
                                                        const float* __restrict__ g2,
                                                        const float* __restrict__ bt2,
                                                        float* __restrict__ w3S,
                                                        float* __restrict__ c3)
{
    __shared__ double tot[1024];
    __shared__ float As[128];
    const int tid = threadIdx.x;
    double sa = 0.0, sb = 0.0;
    for (int blk = 0; blk < 512; ++blk) {
        sa += (double)part[(size_t)blk * 1024 + tid];
        sb += (double)part[(size_t)blk * 1024 + 512 + tid];
    }
    tot[tid] = sa; tot[512 + tid] = sb;
    __syncthreads();
    if (tid < 128) {
        double S = 0.0, Q = 0.0;
        if (tid < 64) {
            for (int g = 0; g < 4; ++g) { S += tot[g * 64 + tid]; Q += tot[256 + g * 64 + tid]; }
        } else {
            const int u = tid - 64;
            for (int g = 0; g < 4; ++g) { S += tot[512 + g * 64 + u]; Q += tot[768 + g * 64 + u]; }
        }
        const double mean = S / (double)MTOT;
        double var = Q / (double)MTOT - mean * mean;
        if (var < 0.0) var = 0.0;
        const double A = (double)g2[tid] / sqrt(var + 1e-5);
        As[tid] = (float)A;
        c3[tid] = (float)((double)bt2[tid] - A * mean);
    }
    __syncthreads();
    for (int i = tid; i < 8192; i += 512) w3S[i] = As[i & 127] * w3T[i];
}

// ---------------------------------------------------------------------------
// Chain kernel: lane owns one point; 64-channel register accumulator; weights
// via wave-uniform scalar loads; h staged in a SELF-OWNED LDS column.
// PHASE 2 = stats of x2nb; PHASE 3 = stats of x3nb (BOTH halves in one pass,
// acc+accB, no recompute); PHASE 4 = final output.
// ---------------------------------------------------------------------------
template<int PHASE>
__global__ __launch_bounds__(256) void chain_kernel(
    const float* __restrict__ v,
    const float* __restrict__ w1S, const float* __restrict__ c1v,
    const float* __restrict__ w2x, const float* __restrict__ c2v,
    const float* __restrict__ w3x, const float* __restrict__ c3v,
    float* __restrict__ part, float* __restrict__ outF, int tpb)
{
    __shared__ float hs[64][256];   // [k][pt] — column tid is self-owned
    const int tid  = threadIdx.x;
    const int lane = tid & 63;
    const int wv   = tid >> 6;
    const int ro   = tid & 63;      // reduce: channel
    const int rg   = tid >> 6;      // reduce: 64-pt group

    float sA = 0.f, qA = 0.f, sB = 0.f, qB = 0.f;

    for (int ti = 0; ti < tpb; ++ti) {
        const int tile = blockIdx.x * tpb + ti;
        const int m = tile * 256 + tid;
        float acc[64];

        auto compute_h1 = [&]() {
#pragma unroll
            for (int o = 0; o < 64; ++o) acc[o] = c1v[o];
            for (int c = 0; c < 6; ++c) {
                const float x = v[(size_t)c * MTOT + m];
                const float* __restrict__ wr = w1S + c * 64;
#pragma unroll
                for (int o = 0; o < 64; ++o) acc[o] = fmaf(wr[o], x, acc[o]);
            }
#pragma unroll
            for (int o = 0; o < 64; ++o) hs[o][tid] = fmaxf(acc[o], 0.f);
        };
        auto l2_loop = [&]() {
#pragma unroll
            for (int o = 0; o < 64; ++o) acc[o] = (PHASE == 2) ? 0.f : c2v[o];
            for (int k = 0; k < 64; ++k) {
                const float h = hs[k][tid];
                const float* __restrict__ wr = w2x + (k << 6);
#pragma unroll
                for (int o = 0; o < 64; ++o) acc[o] = fmaf(wr[o], h, acc[o]);
            }
        };
        auto stats_reduce = [&](const float* a, float& sOut, float& qOut) {
            __syncthreads();
#pragma unroll
            for (int o = 0; o < 64; ++o) hs[o][tid] = a[o];
            __syncthreads();
            float s = 0.f, q = 0.f;
            for (int j = 0; j < 64; ++j) {
                const float x = hs[ro][(rg << 6) + ((j + tid) & 63)];
                s += x; q = fmaf(x, x, q);
            }
            sOut += s; qOut += q;
            __syncthreads();
        };

        compute_h1();
        l2_loop();

        if constexpr (PHASE == 2) {
            stats_reduce(acc, sA, qA);
        } else if constexpr (PHASE == 3) {
            // h2 -> hs
#pragma unroll
            for (int o = 0; o < 64; ++o) hs[o][tid] = fmaxf(acc[o], 0.f);
            // L3 both halves in one pass
            float accB[64];
#pragma unroll
            for (int o = 0; o < 64; ++o) { acc[o] = 0.f; accB[o] = 0.f; }
            for (int k = 0; k < 64; ++k) {
                const float h = hs[k][tid];
                const float* __restrict__ wr = w3x + (k << 7);
#pragma unroll
                for (int o = 0; o < 64; ++o) acc[o]  = fmaf(wr[o], h, acc[o]);
#pragma unroll
                for (int o = 0; o < 64; ++o) accB[o] = fmaf(wr[64 + o], h, accB[o]);
            }
            stats_reduce(acc, sA, qA);
            stats_reduce(accB, sB, qB);
        } else {
            // PHASE 4: h2 -> hs; two L3 halves with folded BN3; group-max
#pragma unroll
            for (int o = 0; o < 64; ++o) hs[o][tid] = fmaxf(acc[o], 0.f);
#pragma unroll
            for (int half = 0; half < 2; ++half) {
#pragma unroll
                for (int o = 0; o < 64; ++o) acc[o] = c3v[(half << 6) + o];
                for (int k = 0; k < 64; ++k) {
                    const float h = hs[k][tid];
                    const float* __restrict__ wr = w3x + (k << 7) + (half << 6);
#pragma unroll
                    for (int o = 0; o < 64; ++o) acc[o] = fmaf(wr[o], h, acc[o]);
                }
#pragma unroll
                for (int o = 0; o < 64; ++o) acc[o] = fmaxf(acc[o], 0.f);
#pragma unroll
                for (int off = 1; off < 32; off <<= 1) {
#pragma unroll
                    for (int o = 0; o < 64; ++o)
                        acc[o] = fmaxf(acc[o], __shfl_xor(acc[o], off));
                }
                if ((lane & 31) == 0) {
                    const int g = tile * 8 + wv * 2 + (lane >> 5);
#pragma unroll
                    for (int og = 0; og < 16; ++og) {
                        f4 t4;
                        t4.v[0] = acc[og * 4 + 0];
                        t4.v[1] = acc[og * 4 + 1];
                        t4.v[2] = acc[og * 4 + 2];
                        t4.v[3] = acc[og * 4 + 3];
                        *reinterpret_cast<f4*>(&outF[(size_t)g * 128 + (half << 6) + og * 4]) = t4;
                    }
                }
            }
        }
    }

    if constexpr (PHASE == 2) {
        part[(size_t)blockIdx.x * 512 + tid]       = sA;
        part[(size_t)blockIdx.x * 512 + 256 + tid] = qA;
    } else if constexpr (PHASE == 3) {
        part[(size_t)blockIdx.x * 1024 + tid]        = sA;
        part[(size_t)blockIdx.x * 1024 + 256 + tid]  = qA;
        part[(size_t)blockIdx.x * 1024 + 512 + tid]  = sB;
        part[(size_t)blockIdx.x * 1024 + 768 + tid]  = qB;
    }
}

// ---------------------------------------------------------------------------
extern "C" void kernel_launch(void* const* d_in, const int* in_sizes, int n_in,
                              void* d_out, int out_size, void* d_ws, size_t ws_size,
                              hipStream_t stream)
{
    const float* xyz  = (const float*)d_in[0];
    const float* feat = (const float*)d_in[1];
    const float* w0  = (const float*)d_in[2];
    const float* g0  = (const float*)d_in[4];
    const float* bt0 = (const float*)d_in[5];
    const float* w1  = (const float*)d_in[6];
    const float* g1  = (const float*)d_in[8];
    const float* bt1 = (const float*)d_in[9];
    const float* w2  = (const float*)d_in[10];
    const float* g2  = (const float*)d_in[12];
    const float* bt2 = (const float*)d_in[13];

    float* out    = (float*)d_out;
    float* newxyz = out;                 // (16,1024,3)
    float* outF   = out + BB * SS * 3;   // (16,1024,128)

    float* wsf  = (float*)d_ws;
    float* v    = wsf;                         // 6*MTOT
    float* part = wsf + 6ull * MTOT;           // max(16384*42, 512*1024) = 688128
    float* w2T  = part + 688128;               // 4096
    float* w3T  = w2T + 4096;                  // 8192
    float* w1S  = w3T + 8192;                  // 384
    float* w2S  = w1S + 384;                   // 4096
    float* w3S  = w2S + 4096;                  // 8192
    float* c1   = w3S + 8192;                  // 64
    float* c2   = c1 + 64;                     // 64
    float* c3   = c2 + 64;                     // 128

    prep_kernel<<<dim3(1), dim3(512), 0, stream>>>(w1, w2, w2T, w3T);
    fps_kernel<<<dim3(BB), dim3(256), 0, stream>>>(xyz, newxyz);
    ball_gather_kernel<<<dim3(4096), dim3(256), 0, stream>>>(xyz, feat, newxyz, v, part);
    finalize1_kernel<<<dim3(1), dim3(512), 0, stream>>>(part, w0, g0, bt0, w1S, c1);

    chain_kernel<2><<<dim3(512), dim3(256), 0, stream>>>(v, w1S, c1, w2T, nullptr,
                                                         nullptr, nullptr, part, nullptr, 4);
    finalize2_kernel<<<dim3(1), dim3(512), 0, stream>>>(part, w2T, g1, bt1, w2S, c2);

    chain_kernel<3><<<dim3(512), dim3(256), 0, stream>>>(v, w1S, c1, w2S, c2,
                                                         w3T, nullptr, part, nullptr, 4);
    finalize3_kernel<<<dim3(1), dim3(512), 0, stream>>>(part, w3T, g2, bt2, w3S, c3);

    chain_kernel<4><<<dim3(512), dim3(256), 0, stream>>>(v, w1S, c1, w2S, c2,
                                                         w3S, c3, nullptr, outF, 4);
}